// Round 4
// baseline (711.447 us; speedup 1.0000x reference)
//
#include <hip/hip_runtime.h>
#include <math.h>

#define Bn 4
#define Sn 2048
#define En 1024
#define Hn 4
#define Dn 256

typedef _Float16 half8 __attribute__((ext_vector_type(8)));
typedef _Float16 half4v __attribute__((ext_vector_type(4)));
typedef float floatx4 __attribute__((ext_vector_type(4)));

#define MFMA16(a, b, c) __builtin_amdgcn_mfma_f32_16x16x32_f16((a), (b), (c), 0, 0, 0)

__device__ __forceinline__ float elup1(float x) {
    return x > 0.0f ? x + 1.0f : __expf(x);
}

// ---------- fp32 -> fp16 elementwise convert (hidden) -----------------------
__global__ void cvt_h_k(const float* __restrict__ src, _Float16* __restrict__ dst, int n4) {
    int idx = blockIdx.x * 256 + threadIdx.x;
    const int stride = gridDim.x * 256;
    for (; idx < n4; idx += stride) {
        float4 v = ((const float4*)src)[idx];
        half4v o;
        o[0] = (_Float16)v.x; o[1] = (_Float16)v.y;
        o[2] = (_Float16)v.z; o[3] = (_Float16)v.w;
        ((half4v*)dst)[idx] = o;
    }
}

// ---------- fp32 [R][C] -> fp16 transposed [C][R], batched ------------------
__global__ __launch_bounds__(256) void trans_f32f16_k(
    const float* __restrict__ src, _Float16* __restrict__ dst, int R, int C) {
    __shared__ float T[64][65];
    const int tid = threadIdx.x;
    const int c0 = blockIdx.x * 64, r0 = blockIdx.y * 64;
    src += (size_t)blockIdx.z * R * C;
    dst += (size_t)blockIdx.z * R * C;
    {
        const int tr = tid >> 2, tc = (tid & 3) * 16;
        const float* s = src + (size_t)(r0 + tr) * C + c0 + tc;
        #pragma unroll
        for (int i = 0; i < 4; ++i) {
            float4 v = *(const float4*)(s + i * 4);
            T[tr][tc + i * 4 + 0] = v.x;
            T[tr][tc + i * 4 + 1] = v.y;
            T[tr][tc + i * 4 + 2] = v.z;
            T[tr][tc + i * 4 + 3] = v.w;
        }
    }
    __syncthreads();
    {
        const int cr = tid >> 2, rc = (tid & 3) * 16;
        half8 h0, h1;
        #pragma unroll
        for (int i = 0; i < 8; ++i) h0[i] = (_Float16)T[rc + i][cr];
        #pragma unroll
        for (int i = 0; i < 8; ++i) h1[i] = (_Float16)T[rc + 8 + i][cr];
        _Float16* d = dst + (size_t)(c0 + cr) * R + r0 + rc;
        *(half8*)d = h0;
        *(half8*)(d + 8) = h1;
    }
}

// ---------- V fp16 [B*S][E] -> Vt fp16 [B*H][D][S] --------------------------
__global__ __launch_bounds__(256) void trans_h16_k(
    const _Float16* __restrict__ Vh, _Float16* __restrict__ Vtg) {
    __shared__ __align__(16) unsigned short T[64 * 72];
    const int tid = threadIdx.x;
    const int s0 = blockIdx.x * 64;
    const int e0 = blockIdx.y * 64;
    const int b = blockIdx.z;
    const int h = e0 >> 8, d0 = e0 & 255;
    {
        const int tr = tid >> 2, tc = (tid & 3) * 16;
        const _Float16* s = Vh + (size_t)(b * Sn + s0 + tr) * En + e0 + tc;
        _Float16* d = (_Float16*)T + tr * 72 + tc;
        *(half8*)d = *(const half8*)s;
        *(half8*)(d + 8) = *(const half8*)(s + 8);
    }
    __syncthreads();
    {
        const int dr = tid >> 2, sc = (tid & 3) * 16;
        const _Float16* Tp = (const _Float16*)T;
        half8 h0, h1;
        #pragma unroll
        for (int i = 0; i < 8; ++i) h0[i] = Tp[(sc + i) * 72 + dr];
        #pragma unroll
        for (int i = 0; i < 8; ++i) h1[i] = Tp[(sc + 8 + i) * 72 + dr];
        _Float16* d = Vtg + (size_t)((b * 4 + h) * 256 + d0 + dr) * (size_t)Sn + s0 + sc;
        *(half8*)d = h0;
        *(half8*)(d + 8) = h1;
    }
}

// ---------- fused GEMM: C[M][N] = A[M][1024] @ Bt[n][k]^T -------------------
// OUT32=false: N=3072, outputs routed to Q/K/V fp16. OUT32=true: N=1024,
// fp32 out + bias. 128x128 tile, BK=64, 4 waves (2x2), 16x16x32 MFMA.
template <bool OUT32>
__global__ __launch_bounds__(256) void gemm_fused_k(
    const _Float16* __restrict__ A, const _Float16* __restrict__ Bt,
    _Float16* __restrict__ Qo, _Float16* __restrict__ Ko, _Float16* __restrict__ Vo,
    float* __restrict__ C32, const float* __restrict__ bias) {
    __shared__ __align__(16) unsigned short Ah[128 * 72];
    __shared__ __align__(16) unsigned short Bh[128 * 72];
    const int tid = threadIdx.x;
    const int lane = tid & 63, w = tid >> 6, quad = lane >> 4, l15 = lane & 15;
    const int bm = blockIdx.y * 128, bn = blockIdx.x * 128;
    const int wr = (w >> 1) * 64, wc = (w & 1) * 64;
    floatx4 acc[4][4];
    #pragma unroll
    for (int mt = 0; mt < 4; ++mt)
        #pragma unroll
        for (int nt = 0; nt < 4; ++nt) acc[mt][nt] = (floatx4){0.f, 0.f, 0.f, 0.f};

    const int srow = tid >> 1, skoff = (tid & 1) * 32;
    const _Float16* as = A + (size_t)(bm + srow) * 1024 + skoff;
    const _Float16* bs = Bt + (size_t)(bn + srow) * 1024 + skoff;
    _Float16* ad = (_Float16*)Ah + srow * 72 + skoff;
    _Float16* bd = (_Float16*)Bh + srow * 72 + skoff;
    const _Float16* AhF = (const _Float16*)Ah;
    const _Float16* BhF = (const _Float16*)Bh;

    for (int k0 = 0; k0 < 1024; k0 += 64) {
        if (k0) __syncthreads();
        #pragma unroll
        for (int u = 0; u < 4; ++u) {
            *(half8*)(ad + u * 8) = *(const half8*)(as + k0 + u * 8);
            *(half8*)(bd + u * 8) = *(const half8*)(bs + k0 + u * 8);
        }
        __syncthreads();
        #pragma unroll
        for (int ks = 0; ks < 2; ++ks) {
            half8 af[4], bf[4];
            #pragma unroll
            for (int mt = 0; mt < 4; ++mt)
                af[mt] = *(const half8*)(AhF + (wr + mt * 16 + l15) * 72 + ks * 32 + quad * 8);
            #pragma unroll
            for (int nt = 0; nt < 4; ++nt)
                bf[nt] = *(const half8*)(BhF + (wc + nt * 16 + l15) * 72 + ks * 32 + quad * 8);
            #pragma unroll
            for (int mt = 0; mt < 4; ++mt)
                #pragma unroll
                for (int nt = 0; nt < 4; ++nt)
                    acc[mt][nt] = MFMA16(af[mt], bf[nt], acc[mt][nt]);
        }
    }
    #pragma unroll
    for (int mt = 0; mt < 4; ++mt)
        #pragma unroll
        for (int nt = 0; nt < 4; ++nt)
            #pragma unroll
            for (int r = 0; r < 4; ++r) {
                const int row = bm + wr + mt * 16 + quad * 4 + r;
                const int col = bn + wc + nt * 16 + l15;
                if constexpr (OUT32) {
                    C32[(size_t)row * 1024 + col] = acc[mt][nt][r] + bias[col];
                } else {
                    const int m = col >> 10, c = col & 1023;
                    _Float16* dst = (m == 0) ? Qo : ((m == 1) ? Ko : Vo);
                    dst[(size_t)row * 1024 + c] = (_Float16)acc[mt][nt][r];
                }
            }
}

// ---------- barrier-free fused flash attention + memory read + gate ---------
// grid (48,16). K/V/mem fragments loaded straight from global (no staging
// LDS, no __syncthreads). l-column via all-ones MFMA; ballot skip of rescale.
__global__ __launch_bounds__(256, 3) void flash_gate_k(
    const _Float16* __restrict__ Qh, const _Float16* __restrict__ Khg,
    const _Float16* __restrict__ Vtg, const _Float16* __restrict__ memT,
    const float* __restrict__ zp, const float* __restrict__ betas,
    _Float16* __restrict__ Cmb, _Float16* __restrict__ Opart,
    float* __restrict__ mpart, float* __restrict__ lpart) {
    __shared__ __align__(16) unsigned short Pb[4 * 16 * 40];
    const int tid = threadIdx.x;
    const int lane = tid & 63;
    const int w = tid >> 6, quad = lane >> 4, l15 = lane & 15;
    const int bx = blockIdx.x, bh = blockIdx.y;
    const int b = bh >> 2, h = bh & 3;

    int qt, kt0, kt1, unit;
    if (bx < 32) {
        qt = 31 - (bx >> 1);
        unit = bx & 1;
        kt0 = unit ? (qt + 1) : 0;
        kt1 = unit ? (2 * qt + 2) : (qt + 1);
    } else {
        qt = 15 - (bx - 32);
        unit = 0;
        kt0 = 0;
        kt1 = 2 * qt + 2;
    }
    const bool two = (bx < 32);
    const int q0 = qt * 64;

    const _Float16* Qrow = Qh + (size_t)(b * Sn + q0 + w * 16 + l15) * En + h * Dn;
    half8 qf[8];
    #pragma unroll
    for (int kc = 0; kc < 8; ++kc) qf[kc] = *(const half8*)(Qrow + kc * 32 + quad * 8);

    floatx4 acc[17];
    #pragma unroll
    for (int nt = 0; nt < 17; ++nt) acc[nt] = (floatx4){0.f, 0.f, 0.f, 0.f};
    half8 ones;
    #pragma unroll
    for (int j = 0; j < 8; ++j) ones[j] = (_Float16)1.0f;

    const float gate = 1.0f / (1.0f + __expf(-betas[h]));
    const float omg = 1.0f - gate;
    _Float16* Cb = Cmb + (size_t)(b * Sn + q0 + w * 16) * En + h * Dn;
    _Float16* PbF = (_Float16*)Pb;

    if (unit == 0) {
        // A_mem = sigma_q @ mem; B-frags straight from global memT
        float denp = 0.0f;
        const _Float16* memh = memT + (size_t)h * Dn * Dn + (size_t)l15 * Dn + quad * 8;
        for (int dc = 0; dc < 8; ++dc) {
            half8 sv;
            const float* zb = zp + h * Dn + dc * 32 + quad * 8;
            #pragma unroll
            for (int j = 0; j < 8; ++j) {
                const float s = elup1((float)qf[dc][j]);
                sv[j] = (_Float16)s;
                denp += s * zb[j];
            }
            #pragma unroll
            for (int nt = 0; nt < 16; ++nt) {
                half8 bmf = *(const half8*)(memh + (size_t)(nt * 16) * Dn + dc * 32);
                acc[nt] = MFMA16(sv, bmf, acc[nt]);
            }
        }
        denp += __shfl_xor(denp, 16);
        denp += __shfl_xor(denp, 32);
        const float deninv = 1.0f / (denp + 1e-6f);
        float den4[4];
        #pragma unroll
        for (int r = 0; r < 4; ++r) den4[r] = __shfl(deninv, quad * 4 + r);
        #pragma unroll
        for (int nt = 0; nt < 16; ++nt)
            #pragma unroll
            for (int r = 0; r < 4; ++r) {
                Cb[(size_t)(quad * 4 + r) * En + nt * 16 + l15] =
                    (_Float16)(gate * acc[nt][r] * den4[r]);
                acc[nt][r] = 0.0f;
            }
    }

    // causal flash loop, K-tile 32, no barriers
    const _Float16* kb0 = Khg + (size_t)(b * Sn + kt0 * 32 + l15) * En + h * Dn + quad * 8;
    const _Float16* kb1 = kb0 + (size_t)16 * En;
    const _Float16* vb = Vtg + (size_t)(bh * 256 + l15) * Sn + kt0 * 32 + quad * 8;
    float mold[4] = {-1e30f, -1e30f, -1e30f, -1e30f};

    for (int kt = kt0; kt < kt1; ++kt) {
        floatx4 S0 = (floatx4){0.f, 0.f, 0.f, 0.f};
        floatx4 S1 = (floatx4){0.f, 0.f, 0.f, 0.f};
        #pragma unroll
        for (int kc = 0; kc < 8; ++kc) {
            half8 kf0 = *(const half8*)(kb0 + kc * 32);
            half8 kf1 = *(const half8*)(kb1 + kc * 32);
            S0 = MFMA16(qf[kc], kf0, S0);
            S1 = MFMA16(qf[kc], kf1, S1);
        }
        kb0 += (size_t)32 * En;
        kb1 += (size_t)32 * En;
        if (kt >= 2 * qt) {
            const int k0 = kt * 32;
            #pragma unroll
            for (int r = 0; r < 4; ++r) {
                const int qg = q0 + w * 16 + quad * 4 + r;
                if (k0 + l15 > qg) S0[r] = -1e30f;
                if (k0 + 16 + l15 > qg) S1[r] = -1e30f;
            }
        }
        float alpha[4];
        bool nr = true;
        #pragma unroll
        for (int r = 0; r < 4; ++r) {
            float mx = fmaxf(S0[r], S1[r]);
            mx = fmaxf(mx, __shfl_xor(mx, 1));
            mx = fmaxf(mx, __shfl_xor(mx, 2));
            mx = fmaxf(mx, __shfl_xor(mx, 4));
            mx = fmaxf(mx, __shfl_xor(mx, 8));
            const float mnew = fmaxf(mold[r], mx);
            alpha[r] = __expf(mold[r] - mnew);
            nr = nr && (mnew == mold[r]);
            mold[r] = mnew;
            const float p0 = __expf(S0[r] - mnew);
            const float p1 = __expf(S1[r] - mnew);
            _Float16* pr = PbF + (w * 16 + quad * 4 + r) * 40;
            pr[l15] = (_Float16)p0;
            pr[16 + l15] = (_Float16)p1;
        }
        if (__ballot(nr) != 0xFFFFFFFFFFFFFFFFull) {
            #pragma unroll
            for (int nt = 0; nt < 17; ++nt) {
                acc[nt][0] *= alpha[0];
                acc[nt][1] *= alpha[1];
                acc[nt][2] *= alpha[2];
                acc[nt][3] *= alpha[3];
            }
        }
        __asm__ volatile("s_waitcnt lgkmcnt(0)" ::: "memory");
        half8 pf = *(const half8*)(PbF + (w * 16 + l15) * 40 + quad * 8);
        #pragma unroll
        for (int nt = 0; nt < 16; ++nt) {
            half8 vf = *(const half8*)(vb + (size_t)(nt * 16) * Sn);
            acc[nt] = MFMA16(pf, vf, acc[nt]);
        }
        acc[16] = MFMA16(pf, ones, acc[16]);
        vb += 32;
    }

    if (!two) {
        #pragma unroll
        for (int r = 0; r < 4; ++r) {
            const float sc = omg / acc[16][r];
            #pragma unroll
            for (int nt = 0; nt < 16; ++nt) {
                const size_t idx = (size_t)(quad * 4 + r) * En + nt * 16 + l15;
                Cb[idx] = (_Float16)((float)Cb[idx] + acc[nt][r] * sc);
            }
        }
    } else {
        const int pidx = ((qt - 16) * 16 + bh) * 2 + unit;
        _Float16* Op = Opart + ((size_t)pidx * 64 + w * 16) * 256;
        #pragma unroll
        for (int nt = 0; nt < 16; ++nt)
            #pragma unroll
            for (int r = 0; r < 4; ++r)
                Op[(quad * 4 + r) * 256 + nt * 16 + l15] = (_Float16)acc[nt][r];
        if (l15 == 0) {
            #pragma unroll
            for (int r = 0; r < 4; ++r) {
                mpart[pidx * 64 + w * 16 + quad * 4 + r] = mold[r];
                lpart[pidx * 64 + w * 16 + quad * 4 + r] = acc[16][r];
            }
        }
    }
}

// ---------- LSE-merge of the two split-K partials (qt >= 16) ----------------
__global__ __launch_bounds__(256) void merge_k(
    const _Float16* __restrict__ Opart, const float* __restrict__ mpart,
    const float* __restrict__ lpart, const float* __restrict__ betas,
    _Float16* __restrict__ Cmb) {
    const int qi = blockIdx.x;
    const int bh = blockIdx.y;
    const int b = bh >> 2, h = bh & 3;
    const int tid = threadIdx.x;
    const int idx = (qi * 16 + bh) * 2;
    const float gate = 1.0f / (1.0f + __expf(-betas[h]));
    const float omg = 1.0f - gate;
    const int rsub = tid >> 6;
    const int c0 = (tid & 63) * 4;
    const _Float16* O0 = Opart + (size_t)idx * 64 * 256;
    const _Float16* O1 = O0 + 64 * 256;
    const int q0 = (16 + qi) * 64;
    for (int chunk = 0; chunk < 16; ++chunk) {
        const int r = chunk * 4 + rsub;
        const float m0 = mpart[idx * 64 + r], l0 = lpart[idx * 64 + r];
        const float m1 = mpart[(idx + 1) * 64 + r], l1 = lpart[(idx + 1) * 64 + r];
        const float mm = fmaxf(m0, m1);
        const float s0 = __expf(m0 - mm), s1 = __expf(m1 - mm);
        const float rl = omg / (l0 * s0 + l1 * s1);
        half4v o0 = *(const half4v*)(O0 + r * 256 + c0);
        half4v o1 = *(const half4v*)(O1 + r * 256 + c0);
        _Float16* cp = Cmb + (size_t)(b * Sn + q0 + r) * En + h * Dn + c0;
        half4v cv = *(half4v*)cp;
        #pragma unroll
        for (int j = 0; j < 4; ++j)
            cv[j] = (_Float16)((float)cv[j] + ((float)o0[j] * s0 + (float)o1[j] * s1) * rl);
        *(half4v*)cp = cv;
    }
}

// ---------- delta: UT = VT - deltaT (in place on Vtg), also emits SkT -------
// grid (32,16): block handles 64 rows s. MFMA sigma_k @ memT; LDS transpose.
__global__ __launch_bounds__(256) void delta_ut_k(
    const _Float16* __restrict__ Kg, _Float16* __restrict__ Vtg,
    _Float16* __restrict__ SkT, const _Float16* __restrict__ memT,
    const float* __restrict__ zp) {
    __shared__ __align__(16) unsigned short L[256 * 72];
    const int tid = threadIdx.x;
    const int lane = tid & 63;
    const int w = tid >> 6, quad = lane >> 4, l15 = lane & 15;
    const int s0 = blockIdx.x * 64;
    const int bh = blockIdx.y;
    const int b = bh >> 2, h = bh & 3;
    _Float16* Lf = (_Float16*)L;

    // sigma_k A-frags + denominator
    const _Float16* Krow = Kg + (size_t)(b * Sn + s0 + w * 16 + l15) * En + h * Dn;
    half8 skf[8];
    float denp = 0.0f;
    #pragma unroll
    for (int kc = 0; kc < 8; ++kc) {
        half8 kv = *(const half8*)(Krow + kc * 32 + quad * 8);
        const float* zb = zp + h * Dn + kc * 32 + quad * 8;
        #pragma unroll
        for (int j = 0; j < 8; ++j) {
            const float s = elup1((float)kv[j]);
            skf[kc][j] = (_Float16)s;
            denp += s * zb[j];
        }
    }
    denp += __shfl_xor(denp, 16);
    denp += __shfl_xor(denp, 32);
    const float deninv = 1.0f / (denp + 1e-6f);
    float den4[4];
    #pragma unroll
    for (int r = 0; r < 4; ++r) den4[r] = __shfl(deninv, quad * 4 + r);

    // delta = sigma_k @ mem via MFMA (B-frags from global memT)
    floatx4 acc[16];
    #pragma unroll
    for (int nt = 0; nt < 16; ++nt) acc[nt] = (floatx4){0.f, 0.f, 0.f, 0.f};
    const _Float16* memh = memT + (size_t)h * Dn * Dn + (size_t)l15 * Dn + quad * 8;
    #pragma unroll
    for (int kc = 0; kc < 8; ++kc)
        #pragma unroll
        for (int nt = 0; nt < 16; ++nt) {
            half8 bmf = *(const half8*)(memh + (size_t)(nt * 16) * Dn + kc * 32);
            acc[nt] = MFMA16(skf[kc], bmf, acc[nt]);
        }

    // deltaT -> LDS [e][s]
    #pragma unroll
    for (int nt = 0; nt < 16; ++nt)
        #pragma unroll
        for (int r = 0; r < 4; ++r)
            Lf[(nt * 16 + l15) * 72 + w * 16 + quad * 4 + r] =
                (_Float16)(acc[nt][r] * den4[r]);
    __syncthreads();
    // UT = VT - deltaT, in place (thread t owns e-row t)
    {
        _Float16* Vrow = Vtg + (size_t)(bh * 256 + tid) * Sn + s0;
        #pragma unroll
        for (int u = 0; u < 8; ++u) {
            half8 v = *(const half8*)(Vrow + u * 8);
            half8 d = *(const half8*)(Lf + tid * 72 + u * 8);
            #pragma unroll
            for (int j = 0; j < 8; ++j) v[j] = v[j] - d[j];
            *(half8*)(Vrow + u * 8) = v;
        }
    }
    __syncthreads();
    // SkT via LDS transpose
    #pragma unroll
    for (int kc = 0; kc < 8; ++kc)
        #pragma unroll
        for (int j = 0; j < 8; ++j)
            Lf[(kc * 32 + quad * 8 + j) * 72 + w * 16 + l15] = skf[kc][j];
    __syncthreads();
    {
        _Float16* Srow = SkT + (size_t)(bh * 256 + tid) * Sn + s0;
        #pragma unroll
        for (int u = 0; u < 8; ++u)
            *(half8*)(Srow + u * 8) = *(const half8*)(Lf + tid * 72 + u * 8);
    }
}

// ---------- mem_new[bh] = mem[h] + SkT @ UT^T  (fp16 MFMA, K=2048) ----------
// grid (4,4,16): 64x64 tile, 4 waves each 16 rows x 64 cols.
__global__ __launch_bounds__(256) void memupd_k(
    const _Float16* __restrict__ SkT, const _Float16* __restrict__ UT,
    const float* __restrict__ memp, float* __restrict__ mem_new) {
    __shared__ __align__(16) unsigned short Ah[64 * 72];
    __shared__ __align__(16) unsigned short Bh[64 * 72];
    const int tid = threadIdx.x;
    const int lane = tid & 63, w = tid >> 6, quad = lane >> 4, l15 = lane & 15;
    const int bn = blockIdx.x * 64, bm = blockIdx.y * 64;
    const int bh = blockIdx.z, h = bh & 3;
    const _Float16* Ab = SkT + (size_t)(bh * 256 + bm) * Sn;
    const _Float16* Bb = UT + (size_t)(bh * 256 + bn) * Sn;
    floatx4 acc[4];
    #pragma unroll
    for (int nt = 0; nt < 4; ++nt) acc[nt] = (floatx4){0.f, 0.f, 0.f, 0.f};

    const int srow = tid >> 2, skoff = (tid & 3) * 16;
    _Float16* ad = (_Float16*)Ah + srow * 72 + skoff;
    _Float16* bd = (_Float16*)Bh + srow * 72 + skoff;
    const _Float16* AhF = (const _Float16*)Ah;
    const _Float16* BhF = (const _Float16*)Bh;

    for (int k0 = 0; k0 < Sn; k0 += 64) {
        if (k0) __syncthreads();
        *(half8*)ad = *(const half8*)(Ab + (size_t)srow * Sn + k0 + skoff);
        *(half8*)(ad + 8) = *(const half8*)(Ab + (size_t)srow * Sn + k0 + skoff + 8);
        *(half8*)bd = *(const half8*)(Bb + (size_t)srow * Sn + k0 + skoff);
        *(half8*)(bd + 8) = *(const half8*)(Bb + (size_t)srow * Sn + k0 + skoff + 8);
        __syncthreads();
        #pragma unroll
        for (int ks = 0; ks < 2; ++ks) {
            half8 af = *(const half8*)(AhF + (w * 16 + l15) * 72 + ks * 32 + quad * 8);
            #pragma unroll
            for (int nt = 0; nt < 4; ++nt) {
                half8 bf = *(const half8*)(BhF + (nt * 16 + l15) * 72 + ks * 32 + quad * 8);
                acc[nt] = MFMA16(af, bf, acc[nt]);
            }
        }
    }
    const float* mh = memp + (size_t)h * Dn * Dn;
    float* mo = mem_new + (size_t)bh * Dn * Dn;
    #pragma unroll
    for (int nt = 0; nt < 4; ++nt)
        #pragma unroll
        for (int r = 0; r < 4; ++r) {
            const int d = bm + w * 16 + quad * 4 + r;
            const int e = bn + nt * 16 + l15;
            mo[(size_t)d * Dn + e] = mh[(size_t)d * Dn + e] + acc[nt][r];
        }
}

// ---------- z_new = z + sum_s sigma_k ---------------------------------------
__global__ __launch_bounds__(256) void znew_init_k(
    const float* __restrict__ zp, float* __restrict__ z_new) {
    const int bh = blockIdx.x;
    const int h = bh & 3;
    z_new[(size_t)bh * Dn + threadIdx.x] = zp[(size_t)h * Dn + threadIdx.x];
}

__global__ __launch_bounds__(256) void znew_acc_k(
    const _Float16* __restrict__ Kg, float* __restrict__ z_new) {
    const int bh = blockIdx.y;
    const int b = bh >> 2;
    const int h = bh & 3;
    const int s0 = blockIdx.x * 256;
    const _Float16* Kb = Kg + (size_t)(b * Sn + s0) * En + h * Dn;
    float acc = 0.0f;
    for (int s = 0; s < 256; ++s) acc += elup1((float)Kb[(size_t)s * En + threadIdx.x]);
    atomicAdd(&z_new[(size_t)bh * Dn + threadIdx.x], acc);
}

extern "C" void kernel_launch(void* const* d_in, const int* in_sizes, int n_in,
                              void* d_out, int out_size, void* d_ws, size_t ws_size,
                              hipStream_t stream) {
    const float* hidden = (const float*)d_in[0];
    const float* Wq = (const float*)d_in[1];
    const float* Wk = (const float*)d_in[2];
    const float* Wv = (const float*)d_in[3];
    const float* Wo = (const float*)d_in[4];
    const float* bo = (const float*)d_in[5];
    const float* betas = (const float*)d_in[6];
    const float* memp = (const float*)d_in[7];
    const float* zp = (const float*)d_in[8];

    float* out = (float*)d_out;                          // [B,S,E]
    float* mem_new = out + (size_t)Bn * Sn * En;         // [B,H,D,D]
    float* z_new = mem_new + (size_t)Bn * Hn * Dn * Dn;  // [B,H,D]

    const size_t BSE = (size_t)Bn * Sn * En;
    _Float16* p = (_Float16*)d_ws;
    _Float16* Qh = p;    p += BSE;
    _Float16* Kh = p;    p += BSE;
    _Float16* Vh = p;    p += BSE;
    _Float16* Vtg = p;   p += BSE;     // V^T, becomes U^T after delta_ut_k
    _Float16* Cmb = p;   p += BSE;
    _Float16* Opart = p; p += BSE;
    _Float16* hh = p;    p += BSE;     // fp16 hidden; reused as SkT after QKV
    _Float16* WqT = p;   p += (size_t)3 * En * En;  // Wq/Wk/Wv transposed, contiguous
    _Float16* WoT = p;   p += (size_t)En * En;
    _Float16* memT = p;  p += (size_t)Hn * Dn * Dn;
    float* fp = (float*)p;
    float* mpart = fp;   fp += 512 * 64;
    float* lpart = fp;   fp += 512 * 64;
    _Float16* SkT = hh;

    trans_f32f16_k<<<dim3(16, 16, 1), 256, 0, stream>>>(Wq, WqT, En, En);
    trans_f32f16_k<<<dim3(16, 16, 1), 256, 0, stream>>>(Wk, WqT + (size_t)En * En, En, En);
    trans_f32f16_k<<<dim3(16, 16, 1), 256, 0, stream>>>(Wv, WqT + (size_t)2 * En * En, En, En);
    trans_f32f16_k<<<dim3(16, 16, 1), 256, 0, stream>>>(Wo, WoT, En, En);
    trans_f32f16_k<<<dim3(4, 4, 4), 256, 0, stream>>>(memp, memT, Dn, Dn);
    cvt_h_k<<<2048, 256, 0, stream>>>(hidden, hh, (int)(BSE / 4));

    gemm_fused_k<false><<<dim3(24, 64), 256, 0, stream>>>(
        hh, WqT, Qh, Kh, Vh, nullptr, nullptr);

    trans_h16_k<<<dim3(32, 16, 4), 256, 0, stream>>>(Vh, Vtg);

    flash_gate_k<<<dim3(48, 16), 256, 0, stream>>>(
        Qh, Kh, Vtg, memT, zp, betas, Cmb, Opart, mpart, lpart);
    merge_k<<<dim3(16, 16), 256, 0, stream>>>(Opart, mpart, lpart, betas, Cmb);

    delta_ut_k<<<dim3(32, 16), 256, 0, stream>>>(Kh, Vtg, SkT, memT, zp);
    memupd_k<<<dim3(4, 4, 16), 256, 0, stream>>>(SkT, Vtg, memp, mem_new);

    znew_init_k<<<16, 256, 0, stream>>>(zp, z_new);
    znew_acc_k<<<dim3(8, 16), 256, 0, stream>>>(Kh, z_new);

    gemm_fused_k<true><<<dim3(8, 64), 256, 0, stream>>>(
        Cmb, WoT, nullptr, nullptr, nullptr, out, bo);
}

// Round 5
// 645.140 us; speedup vs baseline: 1.1028x; 1.1028x over previous
//
#include <hip/hip_runtime.h>
#include <math.h>

#define Bn 4
#define Sn 2048
#define En 1024
#define Hn 4
#define Dn 256

typedef _Float16 half8 __attribute__((ext_vector_type(8)));
typedef _Float16 half4v __attribute__((ext_vector_type(4)));
typedef float floatx4 __attribute__((ext_vector_type(4)));

#define MFMA16(a, b, c) __builtin_amdgcn_mfma_f32_16x16x32_f16((a), (b), (c), 0, 0, 0)

__device__ __forceinline__ float elup1(float x) {
    return x > 0.0f ? x + 1.0f : __expf(x);
}

// ---------- fp32 -> fp16 elementwise convert (hidden) -----------------------
__global__ void cvt_h_k(const float* __restrict__ src, _Float16* __restrict__ dst, int n4) {
    int idx = blockIdx.x * 256 + threadIdx.x;
    const int stride = gridDim.x * 256;
    for (; idx < n4; idx += stride) {
        float4 v = ((const float4*)src)[idx];
        half4v o;
        o[0] = (_Float16)v.x; o[1] = (_Float16)v.y;
        o[2] = (_Float16)v.z; o[3] = (_Float16)v.w;
        ((half4v*)dst)[idx] = o;
    }
}

// ---------- fp32 [R][C] -> fp16 transposed [C][R], batched ------------------
__global__ __launch_bounds__(256) void trans_f32f16_k(
    const float* __restrict__ src, _Float16* __restrict__ dst, int R, int C) {
    __shared__ float T[64][65];
    const int tid = threadIdx.x;
    const int c0 = blockIdx.x * 64, r0 = blockIdx.y * 64;
    src += (size_t)blockIdx.z * R * C;
    dst += (size_t)blockIdx.z * R * C;
    {
        const int tr = tid >> 2, tc = (tid & 3) * 16;
        const float* s = src + (size_t)(r0 + tr) * C + c0 + tc;
        #pragma unroll
        for (int i = 0; i < 4; ++i) {
            float4 v = *(const float4*)(s + i * 4);
            T[tr][tc + i * 4 + 0] = v.x;
            T[tr][tc + i * 4 + 1] = v.y;
            T[tr][tc + i * 4 + 2] = v.z;
            T[tr][tc + i * 4 + 3] = v.w;
        }
    }
    __syncthreads();
    {
        const int cr = tid >> 2, rc = (tid & 3) * 16;
        half8 h0, h1;
        #pragma unroll
        for (int i = 0; i < 8; ++i) h0[i] = (_Float16)T[rc + i][cr];
        #pragma unroll
        for (int i = 0; i < 8; ++i) h1[i] = (_Float16)T[rc + 8 + i][cr];
        _Float16* d = dst + (size_t)(c0 + cr) * R + r0 + rc;
        *(half8*)d = h0;
        *(half8*)(d + 8) = h1;
    }
}

// ---------- V fp16 [B*S][E] -> Vt fp16 [B*H][D][S] --------------------------
__global__ __launch_bounds__(256) void trans_h16_k(
    const _Float16* __restrict__ Vh, _Float16* __restrict__ Vtg) {
    __shared__ __align__(16) unsigned short T[64 * 72];
    const int tid = threadIdx.x;
    const int s0 = blockIdx.x * 64;
    const int e0 = blockIdx.y * 64;
    const int b = blockIdx.z;
    const int h = e0 >> 8, d0 = e0 & 255;
    {
        const int tr = tid >> 2, tc = (tid & 3) * 16;
        const _Float16* s = Vh + (size_t)(b * Sn + s0 + tr) * En + e0 + tc;
        _Float16* d = (_Float16*)T + tr * 72 + tc;
        *(half8*)d = *(const half8*)s;
        *(half8*)(d + 8) = *(const half8*)(s + 8);
    }
    __syncthreads();
    {
        const int dr = tid >> 2, sc = (tid & 3) * 16;
        const _Float16* Tp = (const _Float16*)T;
        half8 h0, h1;
        #pragma unroll
        for (int i = 0; i < 8; ++i) h0[i] = Tp[(sc + i) * 72 + dr];
        #pragma unroll
        for (int i = 0; i < 8; ++i) h1[i] = Tp[(sc + 8 + i) * 72 + dr];
        _Float16* d = Vtg + (size_t)((b * 4 + h) * 256 + d0 + dr) * (size_t)Sn + s0 + sc;
        *(half8*)d = h0;
        *(half8*)(d + 8) = h1;
    }
}

// ---------- fused GEMM: C[M][N] = A[M][1024] @ Bt[n][k]^T -------------------
// OUT32=false: N=3072, outputs routed to Q/K/V fp16. OUT32=true: N=1024,
// fp32 out + bias. 128x128 tile, BK=64, 4 waves (2x2), 16x16x32 MFMA.
template <bool OUT32>
__global__ __launch_bounds__(256) void gemm_fused_k(
    const _Float16* __restrict__ A, const _Float16* __restrict__ Bt,
    _Float16* __restrict__ Qo, _Float16* __restrict__ Ko, _Float16* __restrict__ Vo,
    float* __restrict__ C32, const float* __restrict__ bias) {
    __shared__ __align__(16) unsigned short Ah[128 * 72];
    __shared__ __align__(16) unsigned short Bh[128 * 72];
    const int tid = threadIdx.x;
    const int lane = tid & 63, w = tid >> 6, quad = lane >> 4, l15 = lane & 15;
    const int bm = blockIdx.y * 128, bn = blockIdx.x * 128;
    const int wr = (w >> 1) * 64, wc = (w & 1) * 64;
    floatx4 acc[4][4];
    #pragma unroll
    for (int mt = 0; mt < 4; ++mt)
        #pragma unroll
        for (int nt = 0; nt < 4; ++nt) acc[mt][nt] = (floatx4){0.f, 0.f, 0.f, 0.f};

    const int srow = tid >> 1, skoff = (tid & 1) * 32;
    const _Float16* as = A + (size_t)(bm + srow) * 1024 + skoff;
    const _Float16* bs = Bt + (size_t)(bn + srow) * 1024 + skoff;
    _Float16* ad = (_Float16*)Ah + srow * 72 + skoff;
    _Float16* bd = (_Float16*)Bh + srow * 72 + skoff;
    const _Float16* AhF = (const _Float16*)Ah;
    const _Float16* BhF = (const _Float16*)Bh;

    for (int k0 = 0; k0 < 1024; k0 += 64) {
        if (k0) __syncthreads();
        #pragma unroll
        for (int u = 0; u < 4; ++u) {
            *(half8*)(ad + u * 8) = *(const half8*)(as + k0 + u * 8);
            *(half8*)(bd + u * 8) = *(const half8*)(bs + k0 + u * 8);
        }
        __syncthreads();
        #pragma unroll
        for (int ks = 0; ks < 2; ++ks) {
            half8 af[4], bf[4];
            #pragma unroll
            for (int mt = 0; mt < 4; ++mt)
                af[mt] = *(const half8*)(AhF + (wr + mt * 16 + l15) * 72 + ks * 32 + quad * 8);
            #pragma unroll
            for (int nt = 0; nt < 4; ++nt)
                bf[nt] = *(const half8*)(BhF + (wc + nt * 16 + l15) * 72 + ks * 32 + quad * 8);
            #pragma unroll
            for (int mt = 0; mt < 4; ++mt)
                #pragma unroll
                for (int nt = 0; nt < 4; ++nt)
                    acc[mt][nt] = MFMA16(af[mt], bf[nt], acc[mt][nt]);
        }
    }
    #pragma unroll
    for (int mt = 0; mt < 4; ++mt)
        #pragma unroll
        for (int nt = 0; nt < 4; ++nt)
            #pragma unroll
            for (int r = 0; r < 4; ++r) {
                const int row = bm + wr + mt * 16 + quad * 4 + r;
                const int col = bn + wc + nt * 16 + l15;
                if constexpr (OUT32) {
                    C32[(size_t)row * 1024 + col] = acc[mt][nt][r] + bias[col];
                } else {
                    const int m = col >> 10, c = col & 1023;
                    _Float16* dst = (m == 0) ? Qo : ((m == 1) ? Ko : Vo);
                    dst[(size_t)row * 1024 + c] = (_Float16)acc[mt][nt][r];
                }
            }
}

// ---------- fused flash attention + memory read + gate ----------------------
// grid (48,16), split-K as r3/r4. K tile staged in LDS stride-260 (conflict-
// free), V tile staged chunked [u][d][8] (lane-contiguous writes, uniform-
// bank reads). Register prefetch of next tile; ones-MFMA l; ballot rescale
// skip; wave-private P with lgkm fence only.
__global__ __launch_bounds__(256, 3) void flash_gate_k(
    const _Float16* __restrict__ Qh, const _Float16* __restrict__ Khg,
    const _Float16* __restrict__ Vtg, const _Float16* __restrict__ memT,
    const float* __restrict__ zp, const float* __restrict__ betas,
    _Float16* __restrict__ Cmb, _Float16* __restrict__ Opart,
    float* __restrict__ mpart, float* __restrict__ lpart) {
    __shared__ __align__(16) unsigned short Ksh[32 * 260];
    __shared__ __align__(16) unsigned short Vs[4 * 256 * 8];
    __shared__ __align__(16) unsigned short Pb[64 * 40];

    const int tid = threadIdx.x;
    const int lane = tid & 63;
    const int w = tid >> 6, quad = lane >> 4, l15 = lane & 15;
    const int bx = blockIdx.x, bh = blockIdx.y;
    const int b = bh >> 2, h = bh & 3;

    int qt, kt0, kt1, unit;
    if (bx < 32) {
        qt = 31 - (bx >> 1);
        unit = bx & 1;
        kt0 = unit ? (qt + 1) : 0;
        kt1 = unit ? (2 * qt + 2) : (qt + 1);
    } else {
        qt = 15 - (bx - 32);
        unit = 0;
        kt0 = 0;
        kt1 = 2 * qt + 2;
    }
    const bool two = (bx < 32);
    const int q0 = qt * 64;

    const _Float16* Qrow = Qh + (size_t)(b * Sn + q0 + w * 16 + l15) * En + h * Dn;
    half8 qf[8];
    #pragma unroll
    for (int kc = 0; kc < 8; ++kc) qf[kc] = *(const half8*)(Qrow + kc * 32 + quad * 8);

    floatx4 acc[17];
    #pragma unroll
    for (int nt = 0; nt < 17; ++nt) acc[nt] = (floatx4){0.f, 0.f, 0.f, 0.f};
    half8 ones;
    #pragma unroll
    for (int j = 0; j < 8; ++j) ones[j] = (_Float16)1.0f;

    const float gate = 1.0f / (1.0f + __expf(-betas[h]));
    const float omg = 1.0f - gate;
    _Float16* Cb = Cmb + (size_t)(b * Sn + q0 + w * 16) * En + h * Dn;
    _Float16* KshF = (_Float16*)Ksh;
    _Float16* VsF = (_Float16*)Vs;
    _Float16* PbF = (_Float16*)Pb;

    if (unit == 0) {
        // A_mem = sigma_q @ mem; B-frags straight from global memT (once/block)
        float denp = 0.0f;
        const _Float16* memh = memT + (size_t)h * Dn * Dn + (size_t)l15 * Dn + quad * 8;
        for (int dc = 0; dc < 8; ++dc) {
            half8 sv;
            const float* zb = zp + h * Dn + dc * 32 + quad * 8;
            #pragma unroll
            for (int j = 0; j < 8; ++j) {
                const float s = elup1((float)qf[dc][j]);
                sv[j] = (_Float16)s;
                denp += s * zb[j];
            }
            #pragma unroll
            for (int nt = 0; nt < 16; ++nt) {
                half8 bmf = *(const half8*)(memh + (size_t)(nt * 16) * Dn + dc * 32);
                acc[nt] = MFMA16(sv, bmf, acc[nt]);
            }
        }
        denp += __shfl_xor(denp, 16);
        denp += __shfl_xor(denp, 32);
        const float deninv = 1.0f / (denp + 1e-6f);
        float den4[4];
        #pragma unroll
        for (int r = 0; r < 4; ++r) den4[r] = __shfl(deninv, quad * 4 + r);
        #pragma unroll
        for (int nt = 0; nt < 16; ++nt)
            #pragma unroll
            for (int r = 0; r < 4; ++r) {
                Cb[(size_t)(quad * 4 + r) * En + nt * 16 + l15] =
                    (_Float16)(gate * acc[nt][r] * den4[r]);
                acc[nt][r] = 0.0f;
            }
    }

    // ---- causal flash loop, K-tile 32, LDS-staged with register prefetch
    const _Float16* Kbase = Khg + (size_t)(b * Sn) * En + h * Dn;
    const _Float16* Vtb = Vtg + (size_t)bh * 256 * (size_t)Sn;
    const _Float16* kptr = Kbase + (size_t)(kt0 * 32 + (tid >> 3)) * En + (tid & 7) * 32;
    const _Float16* vptr = Vtb + (size_t)tid * Sn + kt0 * 32;
    half8 kr[4], vr[4];
    #pragma unroll
    for (int u = 0; u < 4; ++u) {
        kr[u] = *(const half8*)(kptr + u * 8);
        vr[u] = *(const half8*)(vptr + u * 8);
    }
    const int kwoff = (tid >> 3) * 260 + (tid & 7) * 32;
    float mold[4] = {-1e30f, -1e30f, -1e30f, -1e30f};

    for (int kt = kt0; kt < kt1; ++kt) {
        const int k0 = kt * 32;
        __syncthreads();  // everyone done reading prev tile
        #pragma unroll
        for (int u = 0; u < 4; ++u) {
            *(half8*)(KshF + kwoff + u * 8) = kr[u];          // uniform banks
            *(half8*)(VsF + (u * 256 + tid) * 8) = vr[u];     // lane-contiguous
        }
        __syncthreads();
        if (kt + 1 < kt1) {  // prefetch next tile; in flight through compute
            kptr += (size_t)32 * En;
            vptr += 32;
            #pragma unroll
            for (int u = 0; u < 4; ++u) {
                kr[u] = *(const half8*)(kptr + u * 8);
                vr[u] = *(const half8*)(vptr + u * 8);
            }
        }

        floatx4 S0 = (floatx4){0.f, 0.f, 0.f, 0.f};
        floatx4 S1 = (floatx4){0.f, 0.f, 0.f, 0.f};
        #pragma unroll
        for (int kc = 0; kc < 8; ++kc) {
            half8 kf0 = *(const half8*)(KshF + l15 * 260 + kc * 32 + quad * 8);
            half8 kf1 = *(const half8*)(KshF + (16 + l15) * 260 + kc * 32 + quad * 8);
            S0 = MFMA16(qf[kc], kf0, S0);
            S1 = MFMA16(qf[kc], kf1, S1);
        }
        if (kt >= 2 * qt) {  // diagonal tiles: causal mask
            #pragma unroll
            for (int r = 0; r < 4; ++r) {
                const int qg = q0 + w * 16 + quad * 4 + r;
                if (k0 + l15 > qg) S0[r] = -1e30f;
                if (k0 + 16 + l15 > qg) S1[r] = -1e30f;
            }
        }
        float alpha[4];
        bool nr = true;
        #pragma unroll
        for (int r = 0; r < 4; ++r) {
            float mx = fmaxf(S0[r], S1[r]);
            mx = fmaxf(mx, __shfl_xor(mx, 1));
            mx = fmaxf(mx, __shfl_xor(mx, 2));
            mx = fmaxf(mx, __shfl_xor(mx, 4));
            mx = fmaxf(mx, __shfl_xor(mx, 8));
            const float mnew = fmaxf(mold[r], mx);
            alpha[r] = __expf(mold[r] - mnew);
            nr = nr && (mnew == mold[r]);
            mold[r] = mnew;
            const float p0 = __expf(S0[r] - mnew);
            const float p1 = __expf(S1[r] - mnew);
            _Float16* pr = PbF + (w * 16 + quad * 4 + r) * 40;
            pr[l15] = (_Float16)p0;
            pr[16 + l15] = (_Float16)p1;
        }
        if (__ballot(nr) != 0xFFFFFFFFFFFFFFFFull) {
            #pragma unroll
            for (int nt = 0; nt < 17; ++nt) {
                acc[nt][0] *= alpha[0];
                acc[nt][1] *= alpha[1];
                acc[nt][2] *= alpha[2];
                acc[nt][3] *= alpha[3];
            }
        }
        // P rows are wave-private: LDS fence only, no block barrier
        __asm__ volatile("s_waitcnt lgkmcnt(0)" ::: "memory");
        half8 pf = *(const half8*)(PbF + (w * 16 + l15) * 40 + quad * 8);
        #pragma unroll
        for (int nt = 0; nt < 16; ++nt) {
            half8 vf = *(const half8*)(VsF + (quad * 256 + nt * 16 + l15) * 8);
            acc[nt] = MFMA16(pf, vf, acc[nt]);
        }
        acc[16] = MFMA16(pf, ones, acc[16]);
    }

    if (!two) {
        #pragma unroll
        for (int r = 0; r < 4; ++r) {
            const float sc = omg / acc[16][r];
            #pragma unroll
            for (int nt = 0; nt < 16; ++nt) {
                const size_t idx = (size_t)(quad * 4 + r) * En + nt * 16 + l15;
                Cb[idx] = (_Float16)((float)Cb[idx] + acc[nt][r] * sc);
            }
        }
    } else {
        const int pidx = ((qt - 16) * 16 + bh) * 2 + unit;
        _Float16* Op = Opart + ((size_t)pidx * 64 + w * 16) * 256;
        #pragma unroll
        for (int nt = 0; nt < 16; ++nt)
            #pragma unroll
            for (int r = 0; r < 4; ++r)
                Op[(quad * 4 + r) * 256 + nt * 16 + l15] = (_Float16)acc[nt][r];
        if (l15 == 0) {
            #pragma unroll
            for (int r = 0; r < 4; ++r) {
                mpart[pidx * 64 + w * 16 + quad * 4 + r] = mold[r];
                lpart[pidx * 64 + w * 16 + quad * 4 + r] = acc[16][r];
            }
        }
    }
}

// ---------- LSE-merge of the two split-K partials (qt >= 16) ----------------
__global__ __launch_bounds__(256) void merge_k(
    const _Float16* __restrict__ Opart, const float* __restrict__ mpart,
    const float* __restrict__ lpart, const float* __restrict__ betas,
    _Float16* __restrict__ Cmb) {
    const int qi = blockIdx.x;
    const int bh = blockIdx.y;
    const int b = bh >> 2, h = bh & 3;
    const int tid = threadIdx.x;
    const int idx = (qi * 16 + bh) * 2;
    const float gate = 1.0f / (1.0f + __expf(-betas[h]));
    const float omg = 1.0f - gate;
    const int rsub = tid >> 6;
    const int c0 = (tid & 63) * 4;
    const _Float16* O0 = Opart + (size_t)idx * 64 * 256;
    const _Float16* O1 = O0 + 64 * 256;
    const int q0 = (16 + qi) * 64;
    for (int chunk = 0; chunk < 16; ++chunk) {
        const int r = chunk * 4 + rsub;
        const float m0 = mpart[idx * 64 + r], l0 = lpart[idx * 64 + r];
        const float m1 = mpart[(idx + 1) * 64 + r], l1 = lpart[(idx + 1) * 64 + r];
        const float mm = fmaxf(m0, m1);
        const float s0 = __expf(m0 - mm), s1 = __expf(m1 - mm);
        const float rl = omg / (l0 * s0 + l1 * s1);
        half4v o0 = *(const half4v*)(O0 + r * 256 + c0);
        half4v o1 = *(const half4v*)(O1 + r * 256 + c0);
        _Float16* cp = Cmb + (size_t)(b * Sn + q0 + r) * En + h * Dn + c0;
        half4v cv = *(half4v*)cp;
        #pragma unroll
        for (int j = 0; j < 4; ++j)
            cv[j] = (_Float16)((float)cv[j] + ((float)o0[j] * s0 + (float)o1[j] * s1) * rl);
        *(half4v*)cp = cv;
    }
}

// ---------- delta: UT = VT - deltaT (in place on Vtg), also emits SkT -------
__global__ __launch_bounds__(256) void delta_ut_k(
    const _Float16* __restrict__ Kg, _Float16* __restrict__ Vtg,
    _Float16* __restrict__ SkT, const _Float16* __restrict__ memT,
    const float* __restrict__ zp) {
    __shared__ __align__(16) unsigned short L[256 * 72];
    const int tid = threadIdx.x;
    const int lane = tid & 63;
    const int w = tid >> 6, quad = lane >> 4, l15 = lane & 15;
    const int s0 = blockIdx.x * 64;
    const int bh = blockIdx.y;
    const int b = bh >> 2, h = bh & 3;
    _Float16* Lf = (_Float16*)L;

    const _Float16* Krow = Kg + (size_t)(b * Sn + s0 + w * 16 + l15) * En + h * Dn;
    half8 skf[8];
    float denp = 0.0f;
    #pragma unroll
    for (int kc = 0; kc < 8; ++kc) {
        half8 kv = *(const half8*)(Krow + kc * 32 + quad * 8);
        const float* zb = zp + h * Dn + kc * 32 + quad * 8;
        #pragma unroll
        for (int j = 0; j < 8; ++j) {
            const float s = elup1((float)kv[j]);
            skf[kc][j] = (_Float16)s;
            denp += s * zb[j];
        }
    }
    denp += __shfl_xor(denp, 16);
    denp += __shfl_xor(denp, 32);
    const float deninv = 1.0f / (denp + 1e-6f);
    float den4[4];
    #pragma unroll
    for (int r = 0; r < 4; ++r) den4[r] = __shfl(deninv, quad * 4 + r);

    floatx4 acc[16];
    #pragma unroll
    for (int nt = 0; nt < 16; ++nt) acc[nt] = (floatx4){0.f, 0.f, 0.f, 0.f};
    const _Float16* memh = memT + (size_t)h * Dn * Dn + (size_t)l15 * Dn + quad * 8;
    #pragma unroll
    for (int kc = 0; kc < 8; ++kc)
        #pragma unroll
        for (int nt = 0; nt < 16; ++nt) {
            half8 bmf = *(const half8*)(memh + (size_t)(nt * 16) * Dn + kc * 32);
            acc[nt] = MFMA16(skf[kc], bmf, acc[nt]);
        }

    #pragma unroll
    for (int nt = 0; nt < 16; ++nt)
        #pragma unroll
        for (int r = 0; r < 4; ++r)
            Lf[(nt * 16 + l15) * 72 + w * 16 + quad * 4 + r] =
                (_Float16)(acc[nt][r] * den4[r]);
    __syncthreads();
    {
        _Float16* Vrow = Vtg + (size_t)(bh * 256 + tid) * Sn + s0;
        #pragma unroll
        for (int u = 0; u < 8; ++u) {
            half8 v = *(const half8*)(Vrow + u * 8);
            half8 d = *(const half8*)(Lf + tid * 72 + u * 8);
            #pragma unroll
            for (int j = 0; j < 8; ++j) v[j] = v[j] - d[j];
            *(half8*)(Vrow + u * 8) = v;
        }
    }
    __syncthreads();
    #pragma unroll
    for (int kc = 0; kc < 8; ++kc)
        #pragma unroll
        for (int j = 0; j < 8; ++j)
            Lf[(kc * 32 + quad * 8 + j) * 72 + w * 16 + l15] = skf[kc][j];
    __syncthreads();
    {
        _Float16* Srow = SkT + (size_t)(bh * 256 + tid) * Sn + s0;
        #pragma unroll
        for (int u = 0; u < 8; ++u)
            *(half8*)(Srow + u * 8) = *(const half8*)(Lf + tid * 72 + u * 8);
    }
}

// ---------- mem_new[bh] = mem[h] + SkT @ UT^T  (fp16 MFMA, K=2048) ----------
__global__ __launch_bounds__(256) void memupd_k(
    const _Float16* __restrict__ SkT, const _Float16* __restrict__ UT,
    const float* __restrict__ memp, float* __restrict__ mem_new) {
    __shared__ __align__(16) unsigned short Ah[64 * 72];
    __shared__ __align__(16) unsigned short Bh[64 * 72];
    const int tid = threadIdx.x;
    const int lane = tid & 63, w = tid >> 6, quad = lane >> 4, l15 = lane & 15;
    const int bn = blockIdx.x * 64, bm = blockIdx.y * 64;
    const int bh = blockIdx.z, h = bh & 3;
    const _Float16* Ab = SkT + (size_t)(bh * 256 + bm) * Sn;
    const _Float16* Bb = UT + (size_t)(bh * 256 + bn) * Sn;
    floatx4 acc[4];
    #pragma unroll
    for (int nt = 0; nt < 4; ++nt) acc[nt] = (floatx4){0.f, 0.f, 0.f, 0.f};

    const int srow = tid >> 2, skoff = (tid & 3) * 16;
    _Float16* ad = (_Float16*)Ah + srow * 72 + skoff;
    _Float16* bd = (_Float16*)Bh + srow * 72 + skoff;
    const _Float16* AhF = (const _Float16*)Ah;
    const _Float16* BhF = (const _Float16*)Bh;

    for (int k0 = 0; k0 < Sn; k0 += 64) {
        if (k0) __syncthreads();
        *(half8*)ad = *(const half8*)(Ab + (size_t)srow * Sn + k0 + skoff);
        *(half8*)(ad + 8) = *(const half8*)(Ab + (size_t)srow * Sn + k0 + skoff + 8);
        *(half8*)bd = *(const half8*)(Bb + (size_t)srow * Sn + k0 + skoff);
        *(half8*)(bd + 8) = *(const half8*)(Bb + (size_t)srow * Sn + k0 + skoff + 8);
        __syncthreads();
        #pragma unroll
        for (int ks = 0; ks < 2; ++ks) {
            half8 af = *(const half8*)(AhF + (w * 16 + l15) * 72 + ks * 32 + quad * 8);
            #pragma unroll
            for (int nt = 0; nt < 4; ++nt) {
                half8 bf = *(const half8*)(BhF + (nt * 16 + l15) * 72 + ks * 32 + quad * 8);
                acc[nt] = MFMA16(af, bf, acc[nt]);
            }
        }
    }
    const float* mh = memp + (size_t)h * Dn * Dn;
    float* mo = mem_new + (size_t)bh * Dn * Dn;
    #pragma unroll
    for (int nt = 0; nt < 4; ++nt)
        #pragma unroll
        for (int r = 0; r < 4; ++r) {
            const int d = bm + w * 16 + quad * 4 + r;
            const int e = bn + nt * 16 + l15;
            mo[(size_t)d * Dn + e] = mh[(size_t)d * Dn + e] + acc[nt][r];
        }
}

// ---------- z_new = z + sum_s sigma_k ---------------------------------------
__global__ __launch_bounds__(256) void znew_init_k(
    const float* __restrict__ zp, float* __restrict__ z_new) {
    const int bh = blockIdx.x;
    const int h = bh & 3;
    z_new[(size_t)bh * Dn + threadIdx.x] = zp[(size_t)h * Dn + threadIdx.x];
}

__global__ __launch_bounds__(256) void znew_acc_k(
    const _Float16* __restrict__ Kg, float* __restrict__ z_new) {
    const int bh = blockIdx.y;
    const int b = bh >> 2;
    const int h = bh & 3;
    const int s0 = blockIdx.x * 256;
    const _Float16* Kb = Kg + (size_t)(b * Sn + s0) * En + h * Dn;
    float acc = 0.0f;
    for (int s = 0; s < 256; ++s) acc += elup1((float)Kb[(size_t)s * En + threadIdx.x]);
    atomicAdd(&z_new[(size_t)bh * Dn + threadIdx.x], acc);
}

extern "C" void kernel_launch(void* const* d_in, const int* in_sizes, int n_in,
                              void* d_out, int out_size, void* d_ws, size_t ws_size,
                              hipStream_t stream) {
    const float* hidden = (const float*)d_in[0];
    const float* Wq = (const float*)d_in[1];
    const float* Wk = (const float*)d_in[2];
    const float* Wv = (const float*)d_in[3];
    const float* Wo = (const float*)d_in[4];
    const float* bo = (const float*)d_in[5];
    const float* betas = (const float*)d_in[6];
    const float* memp = (const float*)d_in[7];
    const float* zp = (const float*)d_in[8];

    float* out = (float*)d_out;                          // [B,S,E]
    float* mem_new = out + (size_t)Bn * Sn * En;         // [B,H,D,D]
    float* z_new = mem_new + (size_t)Bn * Hn * Dn * Dn;  // [B,H,D]

    const size_t BSE = (size_t)Bn * Sn * En;
    _Float16* p = (_Float16*)d_ws;
    _Float16* Qh = p;    p += BSE;
    _Float16* Kh = p;    p += BSE;
    _Float16* Vh = p;    p += BSE;
    _Float16* Vtg = p;   p += BSE;     // V^T, becomes U^T after delta_ut_k
    _Float16* Cmb = p;   p += BSE;
    _Float16* Opart = p; p += BSE;
    _Float16* hh = p;    p += BSE;     // fp16 hidden; reused as SkT after QKV
    _Float16* WqT = p;   p += (size_t)3 * En * En;  // Wq/Wk/Wv transposed, contiguous
    _Float16* WoT = p;   p += (size_t)En * En;
    _Float16* memT = p;  p += (size_t)Hn * Dn * Dn;
    float* fp = (float*)p;
    float* mpart = fp;   fp += 512 * 64;
    float* lpart = fp;   fp += 512 * 64;
    _Float16* SkT = hh;

    trans_f32f16_k<<<dim3(16, 16, 1), 256, 0, stream>>>(Wq, WqT, En, En);
    trans_f32f16_k<<<dim3(16, 16, 1), 256, 0, stream>>>(Wk, WqT + (size_t)En * En, En, En);
    trans_f32f16_k<<<dim3(16, 16, 1), 256, 0, stream>>>(Wv, WqT + (size_t)2 * En * En, En, En);
    trans_f32f16_k<<<dim3(16, 16, 1), 256, 0, stream>>>(Wo, WoT, En, En);
    trans_f32f16_k<<<dim3(4, 4, 4), 256, 0, stream>>>(memp, memT, Dn, Dn);
    cvt_h_k<<<2048, 256, 0, stream>>>(hidden, hh, (int)(BSE / 4));

    gemm_fused_k<false><<<dim3(24, 64), 256, 0, stream>>>(
        hh, WqT, Qh, Kh, Vh, nullptr, nullptr);

    trans_h16_k<<<dim3(32, 16, 4), 256, 0, stream>>>(Vh, Vtg);

    flash_gate_k<<<dim3(48, 16), 256, 0, stream>>>(
        Qh, Kh, Vtg, memT, zp, betas, Cmb, Opart, mpart, lpart);
    merge_k<<<dim3(16, 16), 256, 0, stream>>>(Opart, mpart, lpart, betas, Cmb);

    delta_ut_k<<<dim3(32, 16), 256, 0, stream>>>(Kh, Vtg, SkT, memT, zp);
    memupd_k<<<dim3(4, 4, 16), 256, 0, stream>>>(SkT, Vtg, memp, mem_new);

    znew_init_k<<<16, 256, 0, stream>>>(zp, z_new);
    znew_acc_k<<<dim3(8, 16), 256, 0, stream>>>(Kh, z_new);

    gemm_fused_k<true><<<dim3(8, 64), 256, 0, stream>>>(
        Cmb, WoT, nullptr, nullptr, nullptr, out, bo);
}